// Round 4
// baseline (300.823 us; speedup 1.0000x reference)
//
#include <hip/hip_runtime.h>

#define NNODES 10000
#define NEDGES 160000
#define MUL 16
#define EMB 64
#define HID 128

#define RS128 0.08838834764831845f           // 1/sqrt(128)
#define SC3   (0.08838834764831845f * 0.25f) // 1/sqrt(128) * 1/sqrt(MUL)

typedef __attribute__((ext_vector_type(8))) _Float16 half8;
typedef __attribute__((ext_vector_type(4))) _Float16 half4;
typedef __attribute__((ext_vector_type(4))) float f32x4;
typedef __attribute__((ext_vector_type(16))) float f32x16;

// ---------------------------------------------------------------------------
// Self-connection: initializes every element of out (runs first).
// ---------------------------------------------------------------------------
__global__ __launch_bounds__(256) void selfconn_kernel(
    const float* __restrict__ node_feat,
    const float* __restrict__ sc_w0,
    const float* __restrict__ sc_w1,
    float* __restrict__ out)
{
    const int tid = threadIdx.x;
    const int nl = tid >> 4;
    const int wp = tid & 15;
    const int n  = blockIdx.x * 16 + nl;

    __shared__ float nf[16][64];
    __shared__ float w0s[16][16];
    __shared__ float w1s[16][16];

    ((float4*)nf)[tid] = ((const float4*)(node_feat + (size_t)blockIdx.x * 16 * 64))[tid];
    if (tid < 64)       ((float4*)w0s)[tid]      = ((const float4*)sc_w0)[tid];
    else if (tid < 128) ((float4*)w1s)[tid - 64] = ((const float4*)sc_w1)[tid - 64];
    __syncthreads();

    float o0 = 0.f, o1x = 0.f, o1y = 0.f, o1z = 0.f;
#pragma unroll
    for (int u = 0; u < 16; ++u) {
        o0 += nf[nl][u] * w0s[u][wp];
        const float wv = w1s[u][wp];
        o1x += nf[nl][16 + u * 3 + 0] * wv;
        o1y += nf[nl][16 + u * 3 + 1] * wv;
        o1z += nf[nl][16 + u * 3 + 2] * wv;
    }
    float* op = out + (size_t)n * 64;
    op[wp]              = o0  * 0.25f;
    op[16 + wp * 3 + 0] = o1x * 0.25f;
    op[16 + wp * 3 + 1] = o1y * 0.25f;
    op[16 + wp * 3 + 2] = o1z * 0.25f;
}

// ---------------------------------------------------------------------------
// Prep: pack fc weights fp16 in 32x32x16 MFMA B-fragment order, scales folded.
// Frag f = nt2*KS2 + ks at halfs [(f*64 + lane)*8 + j]:
//   B[k = ks*16 + (lane>>5)*8 + j][n = nt2*32 + (lane&31)]
//   w1p: 4 nt2 x 4 ks  -> [0, 8192)
//   w2p: 4 nt2 x 8 ks  -> [8192, 24576)
//   w3p: 40 nt2 x 8 ks -> [24576, 188416)
// ---------------------------------------------------------------------------
__global__ __launch_bounds__(256) void prep_kernel(
    const float* __restrict__ w1,
    const float* __restrict__ w2,
    const float* __restrict__ w3,
    _Float16* __restrict__ wp)
{
    int idx = blockIdx.x * 256 + threadIdx.x;
    int j = idx & 7, lane = (idx >> 3) & 63;
    int kj  = ((lane >> 5) << 3) + j;   // k within 16-block
    int n32 = lane & 31;
    if (idx < 8192) {
        int f = idx >> 9;               // 0..15
        int nt2 = f >> 2, ks = f & 3;
        wp[idx] = (_Float16)(w1[(ks * 16 + kj) * HID + nt2 * 32 + n32] * 0.125f);
    } else if (idx < 24576) {
        int t = idx - 8192;
        int f = t >> 9;                 // 0..31
        int nt2 = f >> 3, ks = f & 7;
        wp[idx] = (_Float16)(w2[(ks * 16 + kj) * HID + nt2 * 32 + n32] * RS128);
    } else if (idx < 188416) {
        int t = idx - 24576;
        int f = t >> 9;                 // 0..319
        int nt2 = f >> 3, ks = f & 7;
        wp[idx] = (_Float16)(w3[(ks * 16 + kj) * 1280 + nt2 * 32 + n32] * SC3);
    }
}

// ---------------------------------------------------------------------------
// LDS layout (bytes):
//   [0,4096)      ee (fp16 swizzled 128B rows)
//   [4096,12288)  H: xg f32 -> h1 fp16 swz -> h2 fp16 swz (sequenced by barriers)
//   [12288,14592) sA_T  [16][36] f32 (stride 144B)
//   [14592,16896) sB_T  [16][36]
//   [16896,23296) sXY_T [16][100] (x0*y1, stride 400B)
//   [23296,29696) sP3_T [16][100] (x1*y0)
//   [29696,36096) sP4_T [16][100] (cross/sqrt2)
//   [36096,36608) sEF   [32][4]
//   [36608,36864) sidx  [64]
//   opart (4x32x65 f32 = 33280B) aliases [0,33280) after the pair loop.
// ---------------------------------------------------------------------------
#define EE_OFF   0
#define H_OFF    4096
#define SA_OFF   12288
#define SB_OFF   14592
#define SXY_OFF  16896
#define SP3_OFF  23296
#define SP4_OFF  29696
#define SEF_OFF  36096
#define SIDX_OFF 36608
#define SMEM_BYTES 36864
#define OPW 65

__global__ __launch_bounds__(256, 3) void edge_mfma_kernel(
    const int*   __restrict__ ei,
    const float* __restrict__ node_feat,
    const float* __restrict__ edge_feat,
    const float* __restrict__ edge_embed,
    const _Float16* __restrict__ wpk,
    float* __restrict__ out)
{
    __shared__ __align__(16) char smem[SMEM_BYTES];

    const int tid = threadIdx.x;
    const int e0  = blockIdx.x * 32;

    int*   sidxp = (int*)(smem + SIDX_OFF);
    float* sEFp  = (float*)(smem + SEF_OFF);

    // ---- phase 0: indices + edge_feat ----
    if (tid < 32)       sidxp[tid] = ei[e0 + tid];
    else if (tid < 64)  sidxp[tid] = ei[NEDGES + e0 + (tid - 32)];
    else if (tid < 192) {
        int t = tid - 64;
        sEFp[t] = edge_feat[e0 * 4 + t];
    }
    __syncthreads();

    // ---- phase 1: stage edge_embed (fp16, swizzled) + gather node rows ----
    float* xg = (float*)(smem + H_OFF);   // [32][64] f32
    {
        const float4* eesrc = (const float4*)(edge_embed + (size_t)e0 * EMB);
#pragma unroll
        for (int it = 0; it < 2; ++it) {
            int f = tid + it * 256;       // 0..511
            int row = f >> 4, c4 = f & 15;
            float4 v = eesrc[f];
            half4 h = { (_Float16)v.x, (_Float16)v.y, (_Float16)v.z, (_Float16)v.w };
            *(half4*)(smem + EE_OFF + row * 128 + ((c4 * 8) ^ ((row & 7) << 4))) = h;

            int src = sidxp[row];
            float4 nv = ((const float4*)(node_feat + (size_t)src * 64))[c4];
            ((float4*)(xg + row * 64))[c4] = nv;
        }
    }
    __syncthreads();

    // ---- phase 2: per-edge t-vectors, transposed + padded ----
#pragma unroll
    for (int it = 0; it < 2; ++it) {
        int el = (tid >> 4) + it * 16;    // 0..31
        int u  = tid & 15;
        const float* xr = xg + el * 64;
        float x0u = xr[u];
        float xa  = xr[16 + u * 3 + 0];
        float xb  = xr[16 + u * 3 + 1];
        float xc  = xr[16 + u * 3 + 2];
        float y0  = sEFp[el * 4 + 0];
        float y1x = sEFp[el * 4 + 1];
        float y1y = sEFp[el * 4 + 2];
        float y1z = sEFp[el * 4 + 3];
        *(float*)(smem + SA_OFF + u * 144 + el * 4) = x0u * y0;
        *(float*)(smem + SB_OFF + u * 144 + el * 4) =
            (xa * y1x + xb * y1y + xc * y1z) * 0.5773502691896258f;
        float* xy = (float*)(smem + SXY_OFF + u * 400 + el * 12);
        xy[0] = x0u * y1x; xy[1] = x0u * y1y; xy[2] = x0u * y1z;
        float* p3 = (float*)(smem + SP3_OFF + u * 400 + el * 12);
        p3[0] = xa * y0; p3[1] = xb * y0; p3[2] = xc * y0;
        float* p4 = (float*)(smem + SP4_OFF + u * 400 + el * 12);
        p4[0] = (xb * y1z - xc * y1y) * 0.7071067811865476f;
        p4[1] = (xc * y1x - xa * y1z) * 0.7071067811865476f;
        p4[2] = (xa * y1y - xb * y1x) * 0.7071067811865476f;
    }
    __syncthreads();   // xg dead; H region reusable for h1

    const int lane    = tid & 63;
    const int w       = tid >> 6;
    const int col32   = lane & 31;
    const int rowbase = (lane >> 5) << 2;      // 0 or 4
    const int hswzX   = (lane >> 5) * 16;      // byte offset of k-subgroup

    const half8* w1p8 = (const half8*)wpk;
    const half8* w2p8 = (const half8*)(wpk + 8192);
    const half8* w3p8 = (const half8*)(wpk + 24576);

    // ---- GEMM1: h1 = silu(ee @ w1p), one 32-col tile per wave ----
    {
        half8 a[4];
#pragma unroll
        for (int kk = 0; kk < 4; ++kk)
            a[kk] = *(const half8*)(smem + EE_OFF + col32 * 128 +
                                    ((kk * 32 + hswzX) ^ ((col32 & 7) << 4)));
        f32x16 c = {};
#pragma unroll
        for (int kk = 0; kk < 4; ++kk)
            c = __builtin_amdgcn_mfma_f32_32x32x16_f16(a[kk], w1p8[(w * 4 + kk) * 64 + lane], c, 0, 0, 0);
#pragma unroll
        for (int reg = 0; reg < 16; ++reg) {
            int row  = (reg >> 2) * 8 + rowbase + (reg & 3);
            int colg = w * 32 + col32;
            float x = c[reg];
            float s = x / (1.f + __expf(-x));
            *(_Float16*)(smem + H_OFF + row * 256 + ((colg * 2) ^ ((row & 7) << 4))) = (_Float16)s;
        }
    }
    __syncthreads();

    // ---- GEMM2: h2 = silu(h1 @ w2p), written back into H after a barrier ----
    {
        half8 a[8];
#pragma unroll
        for (int kk = 0; kk < 8; ++kk)
            a[kk] = *(const half8*)(smem + H_OFF + col32 * 256 +
                                    ((kk * 32 + hswzX) ^ ((col32 & 7) << 4)));
        f32x16 c = {};
#pragma unroll
        for (int kk = 0; kk < 8; ++kk)
            c = __builtin_amdgcn_mfma_f32_32x32x16_f16(a[kk], w2p8[(w * 8 + kk) * 64 + lane], c, 0, 0, 0);
        __syncthreads();   // all h1 reads complete before overwrite
#pragma unroll
        for (int reg = 0; reg < 16; ++reg) {
            int row  = (reg >> 2) * 8 + rowbase + (reg & 3);
            int colg = w * 32 + col32;
            float x = c[reg];
            float s = x / (1.f + __expf(-x));
            *(_Float16*)(smem + H_OFF + row * 256 + ((colg * 2) ^ ((row & 7) << 4))) = (_Float16)s;
        }
    }
    __syncthreads();

    // ---- GEMM3: 10 32-col pairs per wave, immediate t-contraction ----
    half8 a3[8];
#pragma unroll
    for (int kk = 0; kk < 8; ++kk)
        a3[kk] = *(const half8*)(smem + H_OFF + col32 * 256 +
                                 ((kk * 32 + hswzX) ^ ((col32 & 7) << 4)));

    float acc0[16];
    float acc1[16][3];
#pragma unroll
    for (int r = 0; r < 16; ++r) {
        acc0[r] = 0.f; acc1[r][0] = 0.f; acc1[r][1] = 0.f; acc1[r][2] = 0.f;
    }

    const int uA = col32 >> 4;   // 0 or 1: which u of the pair this lane owns

#define MMP(NT2, C) { \
    const half8* bp = w3p8 + (size_t)(NT2) * 512 + lane; \
    C = __builtin_amdgcn_mfma_f32_32x32x16_f16(a3[0], bp[0],   C, 0, 0, 0); \
    C = __builtin_amdgcn_mfma_f32_32x32x16_f16(a3[1], bp[64],  C, 0, 0, 0); \
    C = __builtin_amdgcn_mfma_f32_32x32x16_f16(a3[2], bp[128], C, 0, 0, 0); \
    C = __builtin_amdgcn_mfma_f32_32x32x16_f16(a3[3], bp[192], C, 0, 0, 0); \
    C = __builtin_amdgcn_mfma_f32_32x32x16_f16(a3[4], bp[256], C, 0, 0, 0); \
    C = __builtin_amdgcn_mfma_f32_32x32x16_f16(a3[5], bp[320], C, 0, 0, 0); \
    C = __builtin_amdgcn_mfma_f32_32x32x16_f16(a3[6], bp[384], C, 0, 0, 0); \
    C = __builtin_amdgcn_mfma_f32_32x32x16_f16(a3[7], bp[448], C, 0, 0, 0); }

#define EPIS(U0, TOFF, C) { \
    const char* tb = smem + (TOFF) + ((U0) + uA) * 144 + rowbase * 4; \
    _Pragma("unroll") \
    for (int rg = 0; rg < 4; ++rg) { \
        f32x4 t = *(const f32x4*)(tb + rg * 32); \
        acc0[rg*4+0] += C[rg*4+0] * t[0]; acc0[rg*4+1] += C[rg*4+1] * t[1]; \
        acc0[rg*4+2] += C[rg*4+2] * t[2]; acc0[rg*4+3] += C[rg*4+3] * t[3]; \
    } }

#define EPIV(U0, TOFF, C) { \
    const char* tb = smem + (TOFF) + ((U0) + uA) * 400 + rowbase * 12; \
    _Pragma("unroll") \
    for (int rg = 0; rg < 4; ++rg) { \
        f32x4 q0 = *(const f32x4*)(tb + rg * 96); \
        f32x4 q1 = *(const f32x4*)(tb + rg * 96 + 16); \
        f32x4 q2 = *(const f32x4*)(tb + rg * 96 + 32); \
        acc1[rg*4+0][0] += C[rg*4+0]*q0[0]; acc1[rg*4+0][1] += C[rg*4+0]*q0[1]; acc1[rg*4+0][2] += C[rg*4+0]*q0[2]; \
        acc1[rg*4+1][0] += C[rg*4+1]*q0[3]; acc1[rg*4+1][1] += C[rg*4+1]*q1[0]; acc1[rg*4+1][2] += C[rg*4+1]*q1[1]; \
        acc1[rg*4+2][0] += C[rg*4+2]*q1[2]; acc1[rg*4+2][1] += C[rg*4+2]*q1[3]; acc1[rg*4+2][2] += C[rg*4+2]*q2[0]; \
        acc1[rg*4+3][0] += C[rg*4+3]*q2[1]; acc1[rg*4+3][1] += C[rg*4+3]*q2[2]; acc1[rg*4+3][2] += C[rg*4+3]*q2[3]; \
    } }

    const int u0a = 2 * w, u0b = 2 * w + 8;
    { f32x16 c = {}; MMP(w,      c); EPIS(u0a, SA_OFF,  c); }
    { f32x16 c = {}; MMP(w + 4,  c); EPIS(u0b, SA_OFF,  c); }
    { f32x16 c = {}; MMP(w + 8,  c); EPIS(u0a, SB_OFF,  c); }
    { f32x16 c = {}; MMP(w + 12, c); EPIS(u0b, SB_OFF,  c); }
    { f32x16 c = {}; MMP(w + 16, c); EPIV(u0a, SXY_OFF, c); }
    { f32x16 c = {}; MMP(w + 20, c); EPIV(u0b, SXY_OFF, c); }
    { f32x16 c = {}; MMP(w + 24, c); EPIV(u0a, SP3_OFF, c); }
    { f32x16 c = {}; MMP(w + 28, c); EPIV(u0b, SP3_OFF, c); }
    { f32x16 c = {}; MMP(w + 32, c); EPIV(u0a, SP4_OFF, c); }
    { f32x16 c = {}; MMP(w + 36, c); EPIV(u0b, SP4_OFF, c); }

#undef MMP
#undef EPIS
#undef EPIV

    // ---- combine the two col-halves (same w', u and u+1) ----
#pragma unroll
    for (int r = 0; r < 16; ++r) {
        acc0[r]    += __shfl_xor(acc0[r], 16);
        acc1[r][0] += __shfl_xor(acc1[r][0], 16);
        acc1[r][1] += __shfl_xor(acc1[r][1], 16);
        acc1[r][2] += __shfl_xor(acc1[r][2], 16);
    }

    __syncthreads();   // all t-array reads done; opart may alias [0,33280)

    if (col32 < 16) {
        float* myop = (float*)smem + w * 32 * OPW;
#pragma unroll
        for (int reg = 0; reg < 16; ++reg) {
            int row = (reg >> 2) * 8 + rowbase + (reg & 3);
            float* rp = myop + row * OPW;
            rp[col32]                = acc0[reg];
            rp[16 + col32 * 3 + 0]   = acc1[reg][0];
            rp[16 + col32 * 3 + 1]   = acc1[reg][1];
            rp[16 + col32 * 3 + 2]   = acc1[reg][2];
        }
    }
    __syncthreads();

    {
        const float* opf = (const float*)smem;
        const int ccol = lane & 15;
        const int rloc = lane >> 4;
#pragma unroll
        for (int rr = 0; rr < 2; ++rr) {
            int row = w * 8 + rr * 4 + rloc;
            int dst = sidxp[32 + row];
            float* op = out + (size_t)dst * 64;
            float v = opf[row * OPW + ccol]        + opf[2080 + row * OPW + ccol]
                    + opf[4160 + row * OPW + ccol] + opf[6240 + row * OPW + ccol];
            atomicAdd(op + ccol, v);
#pragma unroll
            for (int d = 0; d < 3; ++d) {
                int cc = 16 + ccol * 3 + d;
                float v1 = opf[row * OPW + cc]        + opf[2080 + row * OPW + cc]
                         + opf[4160 + row * OPW + cc] + opf[6240 + row * OPW + cc];
                atomicAdd(op + cc, v1);
            }
        }
    }
}

extern "C" void kernel_launch(void* const* d_in, const int* in_sizes, int n_in,
                              void* d_out, int out_size, void* d_ws, size_t ws_size,
                              hipStream_t stream) {
    const int*   ei         = (const int*)  d_in[0];
    const float* node_feat  = (const float*)d_in[1];
    const float* edge_feat  = (const float*)d_in[2];
    const float* edge_embed = (const float*)d_in[3];
    const float* fc_w1      = (const float*)d_in[4];
    const float* fc_w2      = (const float*)d_in[5];
    const float* fc_w3      = (const float*)d_in[6];
    const float* sc_w0      = (const float*)d_in[7];
    const float* sc_w1      = (const float*)d_in[8];
    float* out = (float*)d_out;
    _Float16* wpk = (_Float16*)d_ws;   // 188416 halves = 368 KB

    prep_kernel<<<736, 256, 0, stream>>>(fc_w1, fc_w2, fc_w3, wpk);
    selfconn_kernel<<<NNODES / 16, 256, 0, stream>>>(node_feat, sc_w0, sc_w1, out);
    edge_mfma_kernel<<<NEDGES / 32, 256, 0, stream>>>(ei, node_feat, edge_feat, edge_embed,
                                                      wpk, out);
}

// Round 5
// 150.361 us; speedup vs baseline: 2.0007x; 2.0007x over previous
//
#include <hip/hip_runtime.h>

#define NNODES 10000
#define NEDGES 160000
#define MUL 16
#define EMB 64
#define HID 128

#define RS128 0.08838834764831845f           // 1/sqrt(128)
#define SC3   (0.08838834764831845f * 0.25f) // 1/sqrt(128) * 1/sqrt(MUL)

typedef __attribute__((ext_vector_type(8))) _Float16 half8;
typedef __attribute__((ext_vector_type(4))) _Float16 half4;
typedef __attribute__((ext_vector_type(4))) float f32x4;

// ---------------------------------------------------------------------------
// Self-connection: initializes every element of out (runs first).
// ---------------------------------------------------------------------------
__global__ __launch_bounds__(256) void selfconn_kernel(
    const float* __restrict__ node_feat,
    const float* __restrict__ sc_w0,
    const float* __restrict__ sc_w1,
    float* __restrict__ out)
{
    const int tid = threadIdx.x;
    const int nl = tid >> 4;
    const int wp = tid & 15;
    const int n  = blockIdx.x * 16 + nl;

    __shared__ float nf[16][64];
    __shared__ float w0s[16][16];
    __shared__ float w1s[16][16];

    ((float4*)nf)[tid] = ((const float4*)(node_feat + (size_t)blockIdx.x * 16 * 64))[tid];
    if (tid < 64)       ((float4*)w0s)[tid]      = ((const float4*)sc_w0)[tid];
    else if (tid < 128) ((float4*)w1s)[tid - 64] = ((const float4*)sc_w1)[tid - 64];
    __syncthreads();

    float o0 = 0.f, o1x = 0.f, o1y = 0.f, o1z = 0.f;
#pragma unroll
    for (int u = 0; u < 16; ++u) {
        o0 += nf[nl][u] * w0s[u][wp];
        const float wv = w1s[u][wp];
        o1x += nf[nl][16 + u * 3 + 0] * wv;
        o1y += nf[nl][16 + u * 3 + 1] * wv;
        o1z += nf[nl][16 + u * 3 + 2] * wv;
    }
    float* op = out + (size_t)n * 64;
    op[wp]              = o0  * 0.25f;
    op[16 + wp * 3 + 0] = o1x * 0.25f;
    op[16 + wp * 3 + 1] = o1y * 0.25f;
    op[16 + wp * 3 + 2] = o1z * 0.25f;
}

// ---------------------------------------------------------------------------
// Prep: pack fc weights as fp16 in 16x16x32 MFMA B-fragment order, scales folded.
// half-index = ((nt*KS + ks)*64 + lane)*8 + j ; B[k=ks*32+(lane>>4)*8+j][n=nt*16+(lane&15)]
//   w1p: 8 nt x 2 ks  -> [0, 8192)
//   w2p: 8 nt x 4 ks  -> [8192, 24576)
//   w3p: 80 nt x 4 ks -> [24576, 188416)
// ---------------------------------------------------------------------------
__global__ __launch_bounds__(256) void prep_kernel(
    const float* __restrict__ w1,
    const float* __restrict__ w2,
    const float* __restrict__ w3,
    _Float16* __restrict__ wp)
{
    int idx = blockIdx.x * 256 + threadIdx.x;
    if (idx < 8192) {
        int j = idx & 7, lane = (idx >> 3) & 63, ks = (idx >> 9) & 1, nt = idx >> 10;
        int k = ks * 32 + (lane >> 4) * 8 + j;
        int n = nt * 16 + (lane & 15);
        wp[idx] = (_Float16)(w1[k * HID + n] * 0.125f);
    } else if (idx < 24576) {
        int t = idx - 8192;
        int j = t & 7, lane = (t >> 3) & 63, ks = (t >> 9) & 3, nt = t >> 11;
        int k = ks * 32 + (lane >> 4) * 8 + j;
        int n = nt * 16 + (lane & 15);
        wp[idx] = (_Float16)(w2[k * HID + n] * RS128);
    } else if (idx < 188416) {
        int t = idx - 24576;
        int j = t & 7, lane = (t >> 3) & 63, ks = (t >> 9) & 3, nt = t >> 11;
        int k = ks * 32 + (lane >> 4) * 8 + j;
        int n = nt * 16 + (lane & 15);
        wp[idx] = (_Float16)(w3[k * 1280 + n] * SC3);
    }
}

// ---------------------------------------------------------------------------
// LDS layout (bytes):
//   [0,4096)       ee (fp16, swizzled 128B rows)
//   [4096,12800)   H: xg f32 (rows padded to 68 fl) -> h1 fp16 swz -> h2 fp16 swz
//   [12800,15104)  sA_T  [16][36] f32 (stride 144B)  x0*y0
//   [15104,17408)  sB_T  [16][36]                    dot/sqrt3
//   [17408,23808)  sXY_T [16][100] (stride 400B)     x0*y1
//   [23808,30208)  sP3_T [16][100]                   x1*y0
//   [30208,36608)  sP4_T [16][100]                   cross/sqrt2
//   [36608,37120)  sEF   [32][4]
//   [37120,37376)  sidx  [64]
//   opart (4x32x65 f32 = 33280B) aliases [0,33280) after the tile loop.
// ---------------------------------------------------------------------------
#define EE_OFF   0
#define H_OFF    4096
#define SA_OFF   12800
#define SB_OFF   15104
#define SXY_OFF  17408
#define SP3_OFF  23808
#define SP4_OFF  30208
#define SEF_OFF  36608
#define SIDX_OFF 37120
#define SMEM_BYTES 37376
#define OPW 65

__global__ __launch_bounds__(256, 4) void edge_mfma_kernel(
    const int*   __restrict__ ei,
    const float* __restrict__ node_feat,
    const float* __restrict__ edge_feat,
    const float* __restrict__ edge_embed,
    const _Float16* __restrict__ wpk,
    float* __restrict__ out)
{
    __shared__ __align__(16) char smem[SMEM_BYTES];

    const int tid = threadIdx.x;
    const int e0  = blockIdx.x * 32;

    int*   sidxp = (int*)(smem + SIDX_OFF);
    float* sEFp  = (float*)(smem + SEF_OFF);

    // ---- phase 0: indices + edge_feat ----
    if (tid < 32)       sidxp[tid] = ei[e0 + tid];
    else if (tid < 64)  sidxp[tid] = ei[NEDGES + e0 + (tid - 32)];
    else if (tid < 192) {
        int t = tid - 64;
        sEFp[t] = edge_feat[e0 * 4 + t];
    }
    __syncthreads();

    // ---- phase 1: stage edge_embed (fp16, swizzled) + gather node rows ----
    float* xg = (float*)(smem + H_OFF);   // [32][68] f32 (padded rows)
    {
        const float4* eesrc = (const float4*)(edge_embed + (size_t)e0 * EMB);
#pragma unroll
        for (int it = 0; it < 2; ++it) {
            int f = tid + it * 256;       // 0..511
            int row = f >> 4, c4 = f & 15;
            float4 v = eesrc[f];
            half4 h = { (_Float16)v.x, (_Float16)v.y, (_Float16)v.z, (_Float16)v.w };
            *(half4*)(smem + EE_OFF + row * 128 + ((c4 * 8) ^ ((row & 7) << 4))) = h;

            int src = sidxp[row];
            float4 nv = ((const float4*)(node_feat + (size_t)src * 64))[c4];
            ((float4*)(xg + row * 68))[c4] = nv;
        }
    }
    __syncthreads();

    // ---- phase 2: per-edge t-vectors, transposed + padded (conflict-free) ----
#pragma unroll
    for (int it = 0; it < 2; ++it) {
        int el = (tid >> 4) + it * 16;    // 0..31
        int u  = tid & 15;
        const float* xr = xg + el * 68;
        float x0u = xr[u];
        float xa  = xr[16 + u * 3 + 0];
        float xb  = xr[16 + u * 3 + 1];
        float xc  = xr[16 + u * 3 + 2];
        float y0  = sEFp[el * 4 + 0];
        float y1x = sEFp[el * 4 + 1];
        float y1y = sEFp[el * 4 + 2];
        float y1z = sEFp[el * 4 + 3];
        *(float*)(smem + SA_OFF + u * 144 + el * 4) = x0u * y0;
        *(float*)(smem + SB_OFF + u * 144 + el * 4) =
            (xa * y1x + xb * y1y + xc * y1z) * 0.5773502691896258f;
        float* xy = (float*)(smem + SXY_OFF + u * 400 + el * 12);
        xy[0] = x0u * y1x; xy[1] = x0u * y1y; xy[2] = x0u * y1z;
        float* p3 = (float*)(smem + SP3_OFF + u * 400 + el * 12);
        p3[0] = xa * y0; p3[1] = xb * y0; p3[2] = xc * y0;
        float* p4 = (float*)(smem + SP4_OFF + u * 400 + el * 12);
        p4[0] = (xb * y1z - xc * y1y) * 0.7071067811865476f;
        p4[1] = (xc * y1x - xa * y1z) * 0.7071067811865476f;
        p4[2] = (xa * y1y - xb * y1x) * 0.7071067811865476f;
    }
    __syncthreads();   // xg dead; H region reusable for h1

    const int lane  = tid & 63;
    const int w     = tid >> 6;
    const int wm    = w & 1;
    const int wn    = w >> 1;
    const int aswz  = (lane & 7) << 4;
    const int ako2  = (lane >> 4) * 16;          // byte offset of k-group
    const int ccol  = lane & 15;
    const int crow00 = (lane >> 4) * 4;          // C row base within 16-tile

    const half8* w1p8 = (const half8*)wpk;
    const half8* w2p8 = (const half8*)(wpk + 8192);
    const half8* w3p8 = (const half8*)(wpk + 24576);

    // ---- GEMM1: h1 = silu(ee @ w1p) -> H ----
    {
        const int arow = wm * 16 + (lane & 15);
        half8 a0 = *(const half8*)(smem + EE_OFF + arow * 128 + ((ako2     ) ^ aswz));
        half8 a1 = *(const half8*)(smem + EE_OFF + arow * 128 + ((64 + ako2) ^ aswz));
        const int crow0 = wm * 16 + crow00;
#pragma unroll
        for (int i = 0; i < 4; ++i) {
            int nt = wn * 4 + i;
            f32x4 c = {0.f, 0.f, 0.f, 0.f};
            c = __builtin_amdgcn_mfma_f32_16x16x32_f16(a0, w1p8[(nt * 2 + 0) * 64 + lane], c, 0, 0, 0);
            c = __builtin_amdgcn_mfma_f32_16x16x32_f16(a1, w1p8[(nt * 2 + 1) * 64 + lane], c, 0, 0, 0);
#pragma unroll
            for (int r = 0; r < 4; ++r) {
                int row = crow0 + r;
                int col = nt * 16 + ccol;
                float x = c[r];
                float s = x / (1.f + __expf(-x));
                *(_Float16*)(smem + H_OFF + row * 256 + ((col * 2) ^ ((row & 7) << 4))) = (_Float16)s;
            }
        }
    }
    __syncthreads();

    // ---- GEMM2: h2 = silu(h1 @ w2p), written back into H after a barrier ----
    {
        const int arow = wm * 16 + (lane & 15);
        half8 a2[4];
#pragma unroll
        for (int ks = 0; ks < 4; ++ks)
            a2[ks] = *(const half8*)(smem + H_OFF + arow * 256 + ((ks * 64 + ako2) ^ aswz));
        const int crow0 = wm * 16 + crow00;
        f32x4 cs[4];
#pragma unroll
        for (int i = 0; i < 4; ++i) {
            int nt = wn * 4 + i;
            f32x4 c = {0.f, 0.f, 0.f, 0.f};
#pragma unroll
            for (int ks = 0; ks < 4; ++ks)
                c = __builtin_amdgcn_mfma_f32_16x16x32_f16(a2[ks], w2p8[(nt * 4 + ks) * 64 + lane], c, 0, 0, 0);
            cs[i] = c;
        }
        __syncthreads();   // all h1 reads complete before overwrite
#pragma unroll
        for (int i = 0; i < 4; ++i) {
            int nt = wn * 4 + i;
#pragma unroll
            for (int r = 0; r < 4; ++r) {
                int row = crow0 + r;
                int col = nt * 16 + ccol;
                float x = cs[i][r];
                float s = x / (1.f + __expf(-x));
                *(_Float16*)(smem + H_OFF + row * 256 + ((col * 2) ^ ((row & 7) << 4))) = (_Float16)s;
            }
        }
    }
    __syncthreads();

    // ---- GEMM3: each wave covers BOTH 16-edge M-tiles for 20 nt tiles ----
    half8 a3[2][4];
#pragma unroll
    for (int m = 0; m < 2; ++m) {
        const int arow = m * 16 + (lane & 15);
#pragma unroll
        for (int ks = 0; ks < 4; ++ks)
            a3[m][ks] = *(const half8*)(smem + H_OFF + arow * 256 + ((ks * 64 + ako2) ^ aswz));
    }

    float acc0[2][4] = {{0,0,0,0},{0,0,0,0}};
    float acc1[2][4][3] = {};

#define MM8(NT, C0, C1) { \
    const half8* bp = w3p8 + (size_t)(NT) * 256 + lane; \
    half8 b0 = bp[0], b1 = bp[64], b2 = bp[128], b3 = bp[192]; \
    C0 = __builtin_amdgcn_mfma_f32_16x16x32_f16(a3[0][0], b0, C0, 0, 0, 0); \
    C1 = __builtin_amdgcn_mfma_f32_16x16x32_f16(a3[1][0], b0, C1, 0, 0, 0); \
    C0 = __builtin_amdgcn_mfma_f32_16x16x32_f16(a3[0][1], b1, C0, 0, 0, 0); \
    C1 = __builtin_amdgcn_mfma_f32_16x16x32_f16(a3[1][1], b1, C1, 0, 0, 0); \
    C0 = __builtin_amdgcn_mfma_f32_16x16x32_f16(a3[0][2], b2, C0, 0, 0, 0); \
    C1 = __builtin_amdgcn_mfma_f32_16x16x32_f16(a3[1][2], b2, C1, 0, 0, 0); \
    C0 = __builtin_amdgcn_mfma_f32_16x16x32_f16(a3[0][3], b3, C0, 0, 0, 0); \
    C1 = __builtin_amdgcn_mfma_f32_16x16x32_f16(a3[1][3], b3, C1, 0, 0, 0); }

#define EPI_T(U, TOFF) { \
    const char* tb = smem + (TOFF) + (U) * 144 + crow00 * 4; \
    float4 t0 = *(const float4*)(tb); \
    float4 t1 = *(const float4*)(tb + 64); \
    acc0[0][0] += c0[0] * t0.x; acc0[0][1] += c0[1] * t0.y; \
    acc0[0][2] += c0[2] * t0.z; acc0[0][3] += c0[3] * t0.w; \
    acc0[1][0] += c1[0] * t1.x; acc0[1][1] += c1[1] * t1.y; \
    acc0[1][2] += c1[2] * t1.z; acc0[1][3] += c1[3] * t1.w; }

#define EPI_V(U, TOFF) { \
    const char* tb = smem + (TOFF) + (U) * 400 + crow00 * 12; \
    float4 q0 = *(const float4*)(tb);      \
    float4 q1 = *(const float4*)(tb + 16); \
    float4 q2 = *(const float4*)(tb + 32); \
    acc1[0][0][0] += c0[0]*q0.x; acc1[0][0][1] += c0[0]*q0.y; acc1[0][0][2] += c0[0]*q0.z; \
    acc1[0][1][0] += c0[1]*q0.w; acc1[0][1][1] += c0[1]*q1.x; acc1[0][1][2] += c0[1]*q1.y; \
    acc1[0][2][0] += c0[2]*q1.z; acc1[0][2][1] += c0[2]*q1.w; acc1[0][2][2] += c0[2]*q2.x; \
    acc1[0][3][0] += c0[3]*q2.y; acc1[0][3][1] += c0[3]*q2.z; acc1[0][3][2] += c0[3]*q2.w; \
    float4 p0 = *(const float4*)(tb + 192); \
    float4 p1 = *(const float4*)(tb + 208); \
    float4 p2 = *(const float4*)(tb + 224); \
    acc1[1][0][0] += c1[0]*p0.x; acc1[1][0][1] += c1[0]*p0.y; acc1[1][0][2] += c1[0]*p0.z; \
    acc1[1][1][0] += c1[1]*p0.w; acc1[1][1][1] += c1[1]*p1.x; acc1[1][1][2] += c1[1]*p1.y; \
    acc1[1][2][0] += c1[2]*p1.z; acc1[1][2][1] += c1[2]*p1.w; acc1[1][2][2] += c1[2]*p2.x; \
    acc1[1][3][0] += c1[3]*p2.y; acc1[1][3][1] += c1[3]*p2.z; acc1[1][3][2] += c1[3]*p2.w; }

#define TILE_T(NT, U, TOFF) { \
    f32x4 c0 = {0.f,0.f,0.f,0.f}, c1 = {0.f,0.f,0.f,0.f}; \
    MM8(NT, c0, c1); EPI_T(U, TOFF); }

#define TILE_V(NT, U, TOFF) { \
    f32x4 c0 = {0.f,0.f,0.f,0.f}, c1 = {0.f,0.f,0.f,0.f}; \
    MM8(NT, c0, c1); EPI_V(U, TOFF); }

    switch (w) {
    case 0:
#pragma unroll 4
        for (int u = 0; u < 16; ++u) TILE_T(u, u, SA_OFF);
#pragma unroll
        for (int u = 0; u < 4; ++u)  TILE_T(16 + u, u, SB_OFF);
        break;
    case 1:
#pragma unroll 4
        for (int u = 4; u < 16; ++u) TILE_T(16 + u, u, SB_OFF);
#pragma unroll 4
        for (int u = 0; u < 8; ++u)  TILE_V(32 + u, u, SXY_OFF);
        break;
    case 2:
#pragma unroll 4
        for (int u = 8; u < 16; ++u) TILE_V(32 + u, u, SXY_OFF);
#pragma unroll 4
        for (int u = 0; u < 12; ++u) TILE_V(48 + u, u, SP3_OFF);
        break;
    default:
#pragma unroll
        for (int u = 12; u < 16; ++u) TILE_V(48 + u, u, SP3_OFF);
#pragma unroll 4
        for (int u = 0; u < 16; ++u)  TILE_V(64 + u, u, SP4_OFF);
        break;
    }
#undef MM8
#undef EPI_T
#undef EPI_V
#undef TILE_T
#undef TILE_V

    // ---- cross-wave reduce through LDS (opart aliases [0, 33280)) ----
    __syncthreads();   // all h2 / t-array reads done

    {
        float* myop = (float*)smem + w * 32 * OPW;
#pragma unroll
        for (int m = 0; m < 2; ++m)
#pragma unroll
            for (int r = 0; r < 4; ++r) {
                int row = crow00 + m * 16 + r;
                float* rp = myop + row * OPW;
                rp[ccol]              = acc0[m][r];
                rp[16 + ccol * 3 + 0] = acc1[m][r][0];
                rp[16 + ccol * 3 + 1] = acc1[m][r][1];
                rp[16 + ccol * 3 + 2] = acc1[m][r][2];
            }
    }
    __syncthreads();

    {
        const float* opf = (const float*)smem;
        const int rloc = lane >> 4;
#pragma unroll
        for (int rr = 0; rr < 2; ++rr) {
            int row = w * 8 + rr * 4 + rloc;
            int dst = sidxp[32 + row];
            float* op = out + (size_t)dst * 64;
            float v = opf[row * OPW + ccol]        + opf[2080 + row * OPW + ccol]
                    + opf[4160 + row * OPW + ccol] + opf[6240 + row * OPW + ccol];
            atomicAdd(op + ccol, v);
#pragma unroll
            for (int d = 0; d < 3; ++d) {
                int cc = 16 + ccol * 3 + d;
                float v1 = opf[row * OPW + cc]        + opf[2080 + row * OPW + cc]
                         + opf[4160 + row * OPW + cc] + opf[6240 + row * OPW + cc];
                atomicAdd(op + cc, v1);
            }
        }
    }
}

extern "C" void kernel_launch(void* const* d_in, const int* in_sizes, int n_in,
                              void* d_out, int out_size, void* d_ws, size_t ws_size,
                              hipStream_t stream) {
    const int*   ei         = (const int*)  d_in[0];
    const float* node_feat  = (const float*)d_in[1];
    const float* edge_feat  = (const float*)d_in[2];
    const float* edge_embed = (const float*)d_in[3];
    const float* fc_w1      = (const float*)d_in[4];
    const float* fc_w2      = (const float*)d_in[5];
    const float* fc_w3      = (const float*)d_in[6];
    const float* sc_w0      = (const float*)d_in[7];
    const float* sc_w1      = (const float*)d_in[8];
    float* out = (float*)d_out;
    _Float16* wpk = (_Float16*)d_ws;   // 188416 halves = 368 KB

    prep_kernel<<<736, 256, 0, stream>>>(fc_w1, fc_w2, fc_w3, wpk);
    selfconn_kernel<<<NNODES / 16, 256, 0, stream>>>(node_feat, sc_w0, sc_w1, out);
    edge_mfma_kernel<<<NEDGES / 32, 256, 0, stream>>>(ei, node_feat, edge_feat, edge_embed,
                                                      wpk, out);
}